// Round 15
// baseline (96.588 us; speedup 1.0000x reference)
//
#include <hip/hip_runtime.h>
#include <hip/hip_bf16.h>
#include <float.h>
#include <math.h>

// B=4, S=2048, H=512, k_mul=64. M=B*S=8192.
// Stage 1: GEMM q/k = relu(x)@W^T + b via bf16 MFMA -> bf16 qbf/kbf + kT,
//          + attn zero-fill interleaved in the K-loop (R8 scheme, best
//          measured). NEW vs R8: TM=64 -> 1024 blocks = 4 independent
//          blocks/CU (R8 had 2): independent barriers let other blocks
//          compute while one drains its staging loads (R11/R13 profiles:
//          latency-bound, Occupancy 14-20%, MfmaUtil 5%).
// Stage 2: banded attention, QBLK=16, KW=96, 8 waves; band+out writes only.

typedef __attribute__((ext_vector_type(4))) float f32x4;
typedef __attribute__((ext_vector_type(8))) short short8;
typedef __attribute__((ext_vector_type(4))) short short4v;

#define TM 64
#define TN 128
#define TK 64

#define QBLK 16
#define KW 96      // window; needs k_mul <= KW - QBLK = 80
#define SCP 100    // f32 LDS row stride (pad)
#define PPAD 104   // bf16 LDS row stride

static __device__ __forceinline__ short f2bf(float f) {
    __hip_bfloat16 h = __float2bfloat16(f);  // RNE
    return *reinterpret_cast<short*>(&h);
}

// ---------------- GEMM + in-loop attn zero-fill ----------------
__global__ __launch_bounds__(256) void gemm_mfma_relu_bias_bf16(
    const float* __restrict__ A,
    const float* __restrict__ Wq, const float* __restrict__ bq, short* __restrict__ Cq,
    const float* __restrict__ Wk, const float* __restrict__ bk, short* __restrict__ Ck,
    short* __restrict__ CkT, float* __restrict__ attnz,
    long long zPerBlk4, long long zTotal4,
    int M, int N, int K, int sshift)
{
    const float* W    = blockIdx.z ? Wk : Wq;
    const float* bias = blockIdx.z ? bk : bq;
    short*       C    = blockIdx.z ? Ck : Cq;

    // As [64][64] (8KB) + Bs [128][64] (16KB) = 24KB -> 4 blocks/CU
    __shared__ __align__(16) short lds[(TM + TN) * TK];
    short* As = lds;
    short* Bs = lds + TM * TK;

    const int tid  = threadIdx.x;
    const int lane = tid & 63;
    const int wave = tid >> 6;            // 0..3
    const int wr   = (wave & 1) * 32;     // row offset in 64-row tile
    const int wc   = (wave >> 1) * 64;    // col offset in 128-col tile
    const int m0   = blockIdx.x * TM;
    const int n0   = blockIdx.y * TN;

    // zero-fill bookkeeping (R8 scheme: spread across K-steps)
    const int blkLin = blockIdx.x + gridDim.x * (blockIdx.y + gridDim.y * blockIdx.z);
    f32x4* zp = (f32x4*)attnz;
    const long long zbase = (long long)blkLin * zPerBlk4;
    const int nsteps = K / TK;                       // 8
    const int zPerStep = (int)(zPerBlk4 / nsteps);   // 512 for defaults
    const f32x4 z4 = {0.f, 0.f, 0.f, 0.f};

    const int lr = lane & 15;
    const int lk = (lane >> 4) * 8;
    const int fr = (lane >> 4) * 4;

    f32x4 acc[2][4];
    #pragma unroll
    for (int m = 0; m < 2; ++m)
        #pragma unroll
        for (int n = 0; n < 4; ++n)
            #pragma unroll
            for (int r = 0; r < 4; ++r) acc[m][n][r] = 0.f;

    for (int k0 = 0; k0 < K; k0 += TK) {
        // stage A: 64x64 f32 -> bf16 (relu), 4 float4/thread
        #pragma unroll
        for (int i = 0; i < 4; ++i) {
            int f   = tid + (i << 8);
            int row = f >> 4;
            int cq  = (f & 15) << 2;
            int sidx = row * TK + (cq ^ ((row & 7) << 3));
            float4 va = *(const float4*)&A[(size_t)(m0 + row) * K + k0 + cq];
            short4v sa;
            sa.x = f2bf(fmaxf(va.x, 0.f));
            sa.y = f2bf(fmaxf(va.y, 0.f));
            sa.z = f2bf(fmaxf(va.z, 0.f));
            sa.w = f2bf(fmaxf(va.w, 0.f));
            *(short4v*)&As[sidx] = sa;
        }
        // stage W: 128x64 f32 -> bf16, 8 float4/thread
        #pragma unroll
        for (int i = 0; i < 8; ++i) {
            int f   = tid + (i << 8);
            int row = f >> 4;
            int cq  = (f & 15) << 2;
            int sidx = row * TK + (cq ^ ((row & 7) << 3));
            float4 vb = *(const float4*)&W[(size_t)(n0 + row) * K + k0 + cq];
            short4v sb;
            sb.x = f2bf(vb.x);
            sb.y = f2bf(vb.y);
            sb.z = f2bf(vb.z);
            sb.w = f2bf(vb.w);
            *(short4v*)&Bs[sidx] = sb;
        }
        __syncthreads();

        #pragma unroll
        for (int kk = 0; kk < 2; ++kk) {
            short8 af[2], bf[4];
            #pragma unroll
            for (int m = 0; m < 2; ++m) {
                int r = wr + m * 16 + lr;
                af[m] = *(const short8*)&As[r * TK + ((kk * 32 + lk) ^ ((r & 7) << 3))];
            }
            #pragma unroll
            for (int n = 0; n < 4; ++n) {
                int r = wc + n * 16 + lr;
                bf[n] = *(const short8*)&Bs[r * TK + ((kk * 32 + lk) ^ ((r & 7) << 3))];
            }
            #pragma unroll
            for (int m = 0; m < 2; ++m)
                #pragma unroll
                for (int n = 0; n < 4; ++n)
                    acc[m][n] = __builtin_amdgcn_mfma_f32_16x16x32_bf16(
                        af[m], bf[n], acc[m][n], 0, 0, 0);
        }

        // interleaved attn zero-fill (2 stores/thread/step)
        {
            int s = k0 / TK;
            long long off = zbase + (long long)s * zPerStep + tid;
            for (int j = 0; j < zPerStep; j += 256) {
                long long o = off + j;
                if (o < zTotal4) zp[o] = z4;
            }
        }
        __syncthreads();
    }

    // ---- epilogue: bias add, bf16, LDS-roundtrip for coalesced writes ----
    float bv[4];
    #pragma unroll
    for (int n = 0; n < 4; ++n) bv[n] = bias[n0 + wc + n * 16 + lr];

    #pragma unroll
    for (int m = 0; m < 2; ++m)
        #pragma unroll
        for (int n = 0; n < 4; ++n) {
            int col = wc + n * 16 + lr;
            #pragma unroll
            for (int r = 0; r < 4; ++r) {
                int row = wr + m * 16 + fr + r;
                lds[row * TN + (col ^ ((row & 7) << 3))] = f2bf(acc[m][n][r] + bv[n]);
            }
        }
    __syncthreads();
    #pragma unroll
    for (int i = 0; i < 4; ++i) {
        int idx = tid + (i << 8);
        int m = idx >> 4, n8 = (idx & 15) << 3;
        short8 v = *(const short8*)&lds[m * TN + (n8 ^ ((m & 7) << 3))];
        *(short8*)&C[(size_t)(m0 + m) * N + n0 + n8] = v;
    }

    if (blockIdx.z) {   // K: also emit kT[b][h][s]
        __syncthreads();
        #pragma unroll
        for (int m = 0; m < 2; ++m)
            #pragma unroll
            for (int n = 0; n < 4; ++n) {
                int col = wc + n * 16 + lr;
                #pragma unroll
                for (int r = 0; r < 4; ++r) {
                    int row = wr + m * 16 + fr + r;
                    lds[col * TM + (row ^ ((col & 7) << 3))] = f2bf(acc[m][n][r] + bv[n]);
                }
            }
        __syncthreads();
        const int smask = (1 << sshift) - 1;
        #pragma unroll
        for (int i = 0; i < 4; ++i) {
            int idx = tid + (i << 8);
            int n = idx >> 3, m8 = (idx & 7) << 3;
            short8 v = *(const short8*)&lds[n * TM + (m8 ^ ((n & 7) << 3))];
            int gm = m0 + m8;
            int gb = gm >> sshift, s = gm & smask;
            *(short8*)&CkT[((size_t)gb * N + (n0 + n)) * (size_t)(smask + 1) + s] = v;
        }
    }
}

// ---------------- banded attention (8 waves / 512 threads, QBLK=16) ----------------
__global__ __launch_bounds__(512) void band_attn_mfma(
    const short* __restrict__ qbf, const short* __restrict__ kbf,
    const short* __restrict__ kT, const int* __restrict__ kmul_p,
    float* __restrict__ out, float* __restrict__ attn,
    int S, int H, float scale)
{
    __shared__ float sc[QBLK][SCP];   // scores -> normalized probs (f32)
    __shared__ short pl[QBLK][PPAD];  // probs bf16 for PV A-frags

    // XCD-contiguous tile swizzle (bijective when gridDim.x % 8 == 0).
    int bx = blockIdx.x;
    int tile = bx;
    if ((gridDim.x & 7) == 0) {
        int chunk = gridDim.x >> 3;
        tile = (bx & 7) * chunk + (bx >> 3);
    }

    const int i0  = tile * QBLK;
    const int b   = blockIdx.y;
    const int tid = threadIdx.x;
    const int lane = tid & 63;
    const int w    = tid >> 6;
    const int km   = kmul_p[0];
    const int jbase = max(i0 - (KW - QBLK), 0);   // covers keys [i0-km, i0+QBLK-1]

    const int lr = lane & 15;
    const int lk = (lane >> 4) * 8;
    const int fr = (lane >> 4) * 4;   // frag row base = (lane>>4)*4 + reg

    // ---- scores: D[q][key], waves 0..5 handle keys [16w, 16w+16) ----
    const short* qb = qbf + ((size_t)b * S + i0) * H;
    const short* kb = kbf + ((size_t)b * S + jbase) * H;
    if (w < 6) {
        f32x4 sacc;
        #pragma unroll
        for (int r = 0; r < 4; ++r) sacc[r] = 0.f;
        #pragma unroll
        for (int ks = 0; ks < 16; ++ks) {      // H=512 / 32
            int hoff = ks * 32 + lk;
            short8 qa = *(const short8*)(qb + (size_t)lr * H + hoff);
            short8 kf = *(const short8*)(kb + (size_t)(w * 16 + lr) * H + hoff);
            sacc = __builtin_amdgcn_mfma_f32_16x16x32_bf16(qa, kf, sacc, 0, 0, 0);
        }
        // mask + scale -> sc. key col = lane&15 -> key = 16w + lr.
        int key = w * 16 + lr;
        int kg  = jbase + key;
        #pragma unroll
        for (int r = 0; r < 4; ++r) {
            int q = fr + r;
            int irow = i0 + q;
            bool ok = (kg <= irow) && (kg + km >= irow);
            sc[q][key] = ok ? sacc[r] * scale : -1e30f;
        }
    }
    __syncthreads();

    // ---- softmax: threads 0..255, 16 threads per row, 6 cols each ----
    if (tid < 256) {
        int r = tid >> 4;         // 0..15
        int t = tid & 15;
        float v[6];
        #pragma unroll
        for (int c = 0; c < 6; ++c) v[c] = sc[r][t * 6 + c];
        float mx = -FLT_MAX;
        #pragma unroll
        for (int c = 0; c < 6; ++c) mx = fmaxf(mx, v[c]);
        mx = fmaxf(mx, __shfl_xor(mx, 1, 64));
        mx = fmaxf(mx, __shfl_xor(mx, 2, 64));
        mx = fmaxf(mx, __shfl_xor(mx, 4, 64));
        mx = fmaxf(mx, __shfl_xor(mx, 8, 64));
        float e[6], s = 0.f;
        #pragma unroll
        for (int c = 0; c < 6; ++c) { e[c] = __expf(v[c] - mx); s += e[c]; }
        s += __shfl_xor(s, 1, 64);
        s += __shfl_xor(s, 2, 64);
        s += __shfl_xor(s, 4, 64);
        s += __shfl_xor(s, 8, 64);
        float inv = __frcp_rn(s);
        #pragma unroll
        for (int c = 0; c < 6; ++c) {
            float p = e[c] * inv;
            sc[r][t * 6 + c] = p;
            pl[r][t * 6 + c] = f2bf(p);
        }
    }
    __syncthreads();

    // ---- PV (loads + MFMA + out stores) ----
    short8 pa[3];
    #pragma unroll
    for (int ks = 0; ks < 3; ++ks)
        pa[ks] = *(const short8*)&pl[lr][ks * 32 + lk];

    const short* ktb = kT + (size_t)b * H * S;
    float* obase = out + ((size_t)b * S + i0) * H;
    #pragma unroll
    for (int nf = 0; nf < 4; ++nf) {
        int h = w * 64 + nf * 16 + lr;
        f32x4 oacc;
        #pragma unroll
        for (int r = 0; r < 4; ++r) oacc[r] = 0.f;
        #pragma unroll
        for (int ks = 0; ks < 3; ++ks) {
            short8 kf = *(const short8*)(ktb + (size_t)h * S + jbase + ks * 32 + lk);
            oacc = __builtin_amdgcn_mfma_f32_16x16x32_bf16(pa[ks], kf, oacc, 0, 0, 0);
        }
        #pragma unroll
        for (int r = 0; r < 4; ++r) {
            int q = fr + r;
            __builtin_nontemporal_store(oacc[r], obase + (size_t)q * H + h);
        }
    }

    // ---- band-only attn write (zeros pre-filled by stage-1 fill) ----
    if (tid < (KW / 4) * QBLK) {
        int r = tid / (KW / 4);
        int c = tid % (KW / 4);
        f32x4 o;
        #pragma unroll
        for (int j = 0; j < 4; ++j) o[j] = sc[r][c * 4 + j];
        *(f32x4*)(attn + ((size_t)b * S + i0 + r) * (size_t)S + jbase + c * 4) = o;
    }
}

extern "C" void kernel_launch(void* const* d_in, const int* in_sizes, int n_in,
                              void* d_out, int out_size, void* d_ws, size_t ws_size,
                              hipStream_t stream)
{
    const float* x  = (const float*)d_in[0];
    const float* Wk = (const float*)d_in[1];
    const float* bk = (const float*)d_in[2];
    const float* Wq = (const float*)d_in[3];
    const float* bq = (const float*)d_in[4];
    const int*   km = (const int*)d_in[5];

    const int H = in_sizes[2];                               // 512
    const long long BS = (long long)in_sizes[0] / H;         // 8192
    const long long S = ((long long)out_size - (long long)in_sizes[0]) / BS; // 2048
    const int B = (int)(BS / S);
    int sshift = 0;
    while ((1LL << sshift) < S) ++sshift;                    // S is a power of 2

    // ws layout: kT first (tail reads overrun into qbf: finite bf16),
    // then qbf, then kbf.
    short* kT  = (short*)d_ws;                  // [B][H][S]
    short* qbf = kT + (size_t)B * H * S;        // [BS][H]
    short* kbf = qbf + (size_t)BS * H;          // [BS][H]

    float* outp  = (float*)d_out;
    float* attnp = outp + (size_t)BS * H;

    dim3 gg((unsigned)(BS / TM), (unsigned)(H / TN), 2);
    const long long nblk = (long long)gg.x * gg.y * 2;       // 1024
    const long long zTotal4 = (long long)B * S * S / 4;
    const long long zPerBlk4 = (zTotal4 + nblk - 1) / nblk;  // 4096

    gemm_mfma_relu_bias_bf16<<<gg, 256, 0, stream>>>(
        x, Wq, bq, qbf, Wk, bk, kbf, kT, attnp, zPerBlk4, zTotal4,
        (int)BS, H, H, sshift);

    const float scale = 1.0f / sqrtf((float)H);

    dim3 ag((unsigned)(S / QBLK), (unsigned)B);
    band_attn_mfma<<<ag, 512, 0, stream>>>(qbf, kbf, kT, km, outp, attnp,
                                           (int)S, H, scale);
}

// Round 16
// 49.714 us; speedup vs baseline: 1.9429x; 1.9429x over previous
//
#include <hip/hip_runtime.h>
#include <hip/hip_bf16.h>
#include <float.h>
#include <math.h>

// B=4, S=2048, H=512, k_mul=64. M=B*S=8192.
// R8 structure (best measured: 49.5us), one change: zero-fill stores are
// NONTEMPORAL so the 67MB zero stream doesn't evict x/W from the per-XCD L2
// that the staging loop re-reads.
// Stage 1: GEMM q/k = relu(x)@W^T + b via bf16 MFMA -> bf16 qbf/kbf + kT;
//          attn zero-fill interleaved in the K-loop (4 NT f32x4/thread/step).
// Stage 2: banded attention, QBLK=16, KW=96, 8 waves; band+out writes only.

typedef __attribute__((ext_vector_type(4))) float f32x4;
typedef __attribute__((ext_vector_type(8))) short short8;
typedef __attribute__((ext_vector_type(4))) short short4v;

#define TM 128
#define TN 128
#define TK 64

#define QBLK 16
#define KW 96      // window; needs k_mul <= KW - QBLK = 80
#define SCP 100    // f32 LDS row stride (pad)
#define PPAD 104   // bf16 LDS row stride

static __device__ __forceinline__ short f2bf(float f) {
    __hip_bfloat16 h = __float2bfloat16(f);  // RNE
    return *reinterpret_cast<short*>(&h);
}

// ---------------- GEMM: C = relu(A) @ W^T + bias, bf16 outputs + attn zerofill ----------------
__global__ __launch_bounds__(256) void gemm_mfma_relu_bias_bf16(
    const float* __restrict__ A,
    const float* __restrict__ Wq, const float* __restrict__ bq, short* __restrict__ Cq,
    const float* __restrict__ Wk, const float* __restrict__ bk, short* __restrict__ Ck,
    short* __restrict__ CkT, float* __restrict__ attnz, long long zPerBlk4,
    int M, int N, int K, int sshift)
{
    const float* W    = blockIdx.z ? Wk : Wq;
    const float* bias = blockIdx.z ? bk : bq;
    short*       C    = blockIdx.z ? Ck : Cq;

    __shared__ __align__(16) short lds[TM * TN];   // 32KB; union: staging + epilogue
    short* As = lds;               // [128][64] swizzled
    short* Bs = lds + TM * TK;

    const int tid  = threadIdx.x;
    const int lane = tid & 63;
    const int wave = tid >> 6;
    const int wr   = (wave >> 1) * 64;
    const int wc   = (wave & 1) * 64;
    const int m0   = blockIdx.x * TM;
    const int n0   = blockIdx.y * TN;

    // attn zero-fill bookkeeping: this block owns f32x4 range
    // [blkLin*zPerBlk4, (blkLin+1)*zPerBlk4), split across K-steps.
    const int blkLin = blockIdx.x + gridDim.x * (blockIdx.y + gridDim.y * blockIdx.z);
    f32x4* zp = (f32x4*)attnz;
    const size_t zbase = (size_t)blkLin * (size_t)zPerBlk4;
    const int nsteps = K / TK;
    const int perStep = (int)(zPerBlk4 / ((long long)nsteps * 256));  // 4 for defaults
    const f32x4 z4 = {0.f, 0.f, 0.f, 0.f};

    const int lr = lane & 15;
    const int lk = (lane >> 4) * 8;

    f32x4 acc[4][4];
    #pragma unroll
    for (int m = 0; m < 4; ++m)
        #pragma unroll
        for (int n = 0; n < 4; ++n)
            #pragma unroll
            for (int r = 0; r < 4; ++r) acc[m][n][r] = 0.f;

    for (int k0 = 0; k0 < K; k0 += TK) {
        #pragma unroll
        for (int i = 0; i < 8; ++i) {
            int f   = tid + (i << 8);
            int row = f >> 4;
            int cq  = (f & 15) << 2;
            int sidx = row * TK + (cq ^ ((row & 7) << 3));
            float4 va = *(const float4*)&A[(size_t)(m0 + row) * K + k0 + cq];
            short4v sa;
            sa.x = f2bf(fmaxf(va.x, 0.f));
            sa.y = f2bf(fmaxf(va.y, 0.f));
            sa.z = f2bf(fmaxf(va.z, 0.f));
            sa.w = f2bf(fmaxf(va.w, 0.f));
            *(short4v*)&As[sidx] = sa;
            float4 vb = *(const float4*)&W[(size_t)(n0 + row) * K + k0 + cq];
            short4v sb;
            sb.x = f2bf(vb.x);
            sb.y = f2bf(vb.y);
            sb.z = f2bf(vb.z);
            sb.w = f2bf(vb.w);
            *(short4v*)&Bs[sidx] = sb;
        }
        __syncthreads();

        #pragma unroll
        for (int kk = 0; kk < 2; ++kk) {
            short8 af[4], bf[4];
            #pragma unroll
            for (int m = 0; m < 4; ++m) {
                int r = wr + m * 16 + lr;
                af[m] = *(const short8*)&As[r * TK + ((kk * 32 + lk) ^ ((r & 7) << 3))];
            }
            #pragma unroll
            for (int n = 0; n < 4; ++n) {
                int r = wc + n * 16 + lr;
                bf[n] = *(const short8*)&Bs[r * TK + ((kk * 32 + lk) ^ ((r & 7) << 3))];
            }
            #pragma unroll
            for (int m = 0; m < 4; ++m)
                #pragma unroll
                for (int n = 0; n < 4; ++n)
                    acc[m][n] = __builtin_amdgcn_mfma_f32_16x16x32_bf16(
                        af[m], bf[n], acc[m][n], 0, 0, 0);
        }

        // interleaved attn zero-fill: NONTEMPORAL so 67MB of zeros stream
        // past the per-XCD L2 instead of evicting x/W staging lines.
        {
            int s = k0 / TK;
            size_t off = zbase + (size_t)s * perStep * 256 + tid;
            for (int j = 0; j < perStep; ++j)
                __builtin_nontemporal_store(z4, &zp[off + (size_t)j * 256]);
        }
        __syncthreads();
    }

    // ---- epilogue: bias add, bf16, LDS-roundtrip for coalesced writes ----
    float bv[4];
    #pragma unroll
    for (int n = 0; n < 4; ++n) bv[n] = bias[n0 + wc + n * 16 + lr];
    const int cr = (lane >> 4) * 4;

    #pragma unroll
    for (int m = 0; m < 4; ++m)
        #pragma unroll
        for (int n = 0; n < 4; ++n) {
            int col = wc + n * 16 + lr;
            #pragma unroll
            for (int r = 0; r < 4; ++r) {
                int row = wr + m * 16 + cr + r;
                lds[row * TN + (col ^ ((row & 7) << 3))] = f2bf(acc[m][n][r] + bv[n]);
            }
        }
    __syncthreads();
    #pragma unroll
    for (int i = 0; i < 8; ++i) {
        int idx = tid + (i << 8);
        int m = idx >> 4, n8 = (idx & 15) << 3;
        short8 v = *(const short8*)&lds[m * TN + (n8 ^ ((m & 7) << 3))];
        *(short8*)&C[(size_t)(m0 + m) * N + n0 + n8] = v;
    }

    if (blockIdx.z) {   // K: also emit kT[b][h][s]
        __syncthreads();
        #pragma unroll
        for (int m = 0; m < 4; ++m)
            #pragma unroll
            for (int n = 0; n < 4; ++n) {
                int col = wc + n * 16 + lr;
                #pragma unroll
                for (int r = 0; r < 4; ++r) {
                    int row = wr + m * 16 + cr + r;
                    lds[col * TM + (row ^ ((col & 7) << 3))] = f2bf(acc[m][n][r] + bv[n]);
                }
            }
        __syncthreads();
        const int smask = (1 << sshift) - 1;
        #pragma unroll
        for (int i = 0; i < 8; ++i) {
            int idx = tid + (i << 8);
            int n = idx >> 4, m8 = (idx & 15) << 3;
            short8 v = *(const short8*)&lds[n * TM + (m8 ^ ((n & 7) << 3))];
            int gm = m0 + m8;
            int gb = gm >> sshift, s = gm & smask;
            *(short8*)&CkT[((size_t)gb * N + (n0 + n)) * (size_t)(smask + 1) + s] = v;
        }
    }
}

// ---------------- banded attention (8 waves / 512 threads, QBLK=16) ----------------
__global__ __launch_bounds__(512) void band_attn_mfma(
    const short* __restrict__ qbf, const short* __restrict__ kbf,
    const short* __restrict__ kT, const int* __restrict__ kmul_p,
    float* __restrict__ out, float* __restrict__ attn,
    int S, int H, float scale)
{
    __shared__ float sc[QBLK][SCP];   // scores -> normalized probs (f32)
    __shared__ short pl[QBLK][PPAD];  // probs bf16 for PV A-frags

    // XCD-contiguous tile swizzle (bijective when gridDim.x % 8 == 0).
    int bx = blockIdx.x;
    int tile = bx;
    if ((gridDim.x & 7) == 0) {
        int chunk = gridDim.x >> 3;
        tile = (bx & 7) * chunk + (bx >> 3);
    }

    const int i0  = tile * QBLK;
    const int b   = blockIdx.y;
    const int tid = threadIdx.x;
    const int lane = tid & 63;
    const int w    = tid >> 6;
    const int km   = kmul_p[0];
    const int jbase = max(i0 - (KW - QBLK), 0);   // covers keys [i0-km, i0+QBLK-1]

    const int lr = lane & 15;
    const int lk = (lane >> 4) * 8;
    const int fr = (lane >> 4) * 4;   // frag row base = (lane>>4)*4 + reg

    // ---- scores: D[q][key], waves 0..5 handle keys [16w, 16w+16) ----
    const short* qb = qbf + ((size_t)b * S + i0) * H;
    const short* kb = kbf + ((size_t)b * S + jbase) * H;
    if (w < 6) {
        f32x4 sacc;
        #pragma unroll
        for (int r = 0; r < 4; ++r) sacc[r] = 0.f;
        #pragma unroll
        for (int ks = 0; ks < 16; ++ks) {      // H=512 / 32
            int hoff = ks * 32 + lk;
            short8 qa = *(const short8*)(qb + (size_t)lr * H + hoff);
            short8 kf = *(const short8*)(kb + (size_t)(w * 16 + lr) * H + hoff);
            sacc = __builtin_amdgcn_mfma_f32_16x16x32_bf16(qa, kf, sacc, 0, 0, 0);
        }
        // mask + scale -> sc. key col = lane&15 -> key = 16w + lr.
        int key = w * 16 + lr;
        int kg  = jbase + key;
        #pragma unroll
        for (int r = 0; r < 4; ++r) {
            int q = fr + r;
            int irow = i0 + q;
            bool ok = (kg <= irow) && (kg + km >= irow);
            sc[q][key] = ok ? sacc[r] * scale : -1e30f;
        }
    }
    __syncthreads();

    // ---- softmax: threads 0..255, 16 threads per row, 6 cols each ----
    if (tid < 256) {
        int r = tid >> 4;         // 0..15
        int t = tid & 15;
        float v[6];
        #pragma unroll
        for (int c = 0; c < 6; ++c) v[c] = sc[r][t * 6 + c];
        float mx = -FLT_MAX;
        #pragma unroll
        for (int c = 0; c < 6; ++c) mx = fmaxf(mx, v[c]);
        mx = fmaxf(mx, __shfl_xor(mx, 1, 64));
        mx = fmaxf(mx, __shfl_xor(mx, 2, 64));
        mx = fmaxf(mx, __shfl_xor(mx, 4, 64));
        mx = fmaxf(mx, __shfl_xor(mx, 8, 64));
        float e[6], s = 0.f;
        #pragma unroll
        for (int c = 0; c < 6; ++c) { e[c] = __expf(v[c] - mx); s += e[c]; }
        s += __shfl_xor(s, 1, 64);
        s += __shfl_xor(s, 2, 64);
        s += __shfl_xor(s, 4, 64);
        s += __shfl_xor(s, 8, 64);
        float inv = __frcp_rn(s);
        #pragma unroll
        for (int c = 0; c < 6; ++c) {
            float p = e[c] * inv;
            sc[r][t * 6 + c] = p;
            pl[r][t * 6 + c] = f2bf(p);
        }
    }
    __syncthreads();

    // ---- PV (loads + MFMA + out stores) ----
    short8 pa[3];
    #pragma unroll
    for (int ks = 0; ks < 3; ++ks)
        pa[ks] = *(const short8*)&pl[lr][ks * 32 + lk];

    const short* ktb = kT + (size_t)b * H * S;
    float* obase = out + ((size_t)b * S + i0) * H;
    #pragma unroll
    for (int nf = 0; nf < 4; ++nf) {
        int h = w * 64 + nf * 16 + lr;
        f32x4 oacc;
        #pragma unroll
        for (int r = 0; r < 4; ++r) oacc[r] = 0.f;
        #pragma unroll
        for (int ks = 0; ks < 3; ++ks) {
            short8 kf = *(const short8*)(ktb + (size_t)h * S + jbase + ks * 32 + lk);
            oacc = __builtin_amdgcn_mfma_f32_16x16x32_bf16(pa[ks], kf, oacc, 0, 0, 0);
        }
        #pragma unroll
        for (int r = 0; r < 4; ++r) {
            int q = fr + r;
            __builtin_nontemporal_store(oacc[r], obase + (size_t)q * H + h);
        }
    }

    // ---- band-only attn write (zeros pre-filled by GEMM kernel) ----
    // KW/4 = 24 f32x4 per row, QBLK=16 rows -> 384 threads, one f32x4 each.
    if (tid < (KW / 4) * QBLK) {
        int r = tid / (KW / 4);
        int c = tid % (KW / 4);
        f32x4 o;
        #pragma unroll
        for (int j = 0; j < 4; ++j) o[j] = sc[r][c * 4 + j];
        *(f32x4*)(attn + ((size_t)b * S + i0 + r) * (size_t)S + jbase + c * 4) = o;
    }
}

extern "C" void kernel_launch(void* const* d_in, const int* in_sizes, int n_in,
                              void* d_out, int out_size, void* d_ws, size_t ws_size,
                              hipStream_t stream)
{
    const float* x  = (const float*)d_in[0];
    const float* Wk = (const float*)d_in[1];
    const float* bk = (const float*)d_in[2];
    const float* Wq = (const float*)d_in[3];
    const float* bq = (const float*)d_in[4];
    const int*   km = (const int*)d_in[5];

    const int H = in_sizes[2];                               // 512
    const long long BS = (long long)in_sizes[0] / H;         // 8192
    const long long S = ((long long)out_size - (long long)in_sizes[0]) / BS; // 2048
    const int B = (int)(BS / S);
    int sshift = 0;
    while ((1LL << sshift) < S) ++sshift;                    // S is a power of 2

    // ws layout: kT first (tail reads overrun into qbf: finite bf16),
    // then qbf, then kbf.
    short* kT  = (short*)d_ws;                  // [B][H][S]
    short* qbf = kT + (size_t)B * H * S;        // [BS][H]
    short* kbf = qbf + (size_t)BS * H;          // [BS][H]

    float* outp  = (float*)d_out;
    float* attnp = outp + (size_t)BS * H;

    dim3 gg((unsigned)(BS / TM), (unsigned)(H / TN), 2);
    const long long nblk = (long long)gg.x * gg.y * 2;
    const long long zPerBlk4 = ((long long)B * S * S / 4) / nblk;  // 8192 default

    gemm_mfma_relu_bias_bf16<<<gg, 256, 0, stream>>>(
        x, Wq, bq, qbf, Wk, bk, kbf, kT, attnp, zPerBlk4,
        (int)BS, H, H, sshift);

    const float scale = 1.0f / sqrtf((float)H);

    dim3 ag((unsigned)(S / QBLK), (unsigned)B);
    band_attn_mfma<<<ag, 512, 0, stream>>>(qbf, kbf, kT, km, outp, attnp,
                                           (int)S, H, scale);
}